// Round 12
// baseline (196.869 us; speedup 1.0000x reference)
//
#include <hip/hip_runtime.h>

#define N_ROWS 32768
#define DIM 256
#define KCODES 1024

#define Q_N (N_ROWS * DIM)          // 8388608
#define IDX_OFF Q_N                 // 8388608
#define ZERO_OFF (Q_N + N_ROWS)     // 8421376
#define LOSS_OFF (ZERO_OFF + 1)
#define PERP_OFF (ZERO_OFF + 2)

// Scaled-acc units: acc' = 512 + 512*sen - 1024*dot  (=1024*(score/2) + 512).
// np flip window = 3.05e-5 acc = 0.031 scaled; fp16 fast-path 5-sigma error
// ~1.5e-5 acc = 0.015 scaled (rms 2.6e-6). AMBIG 0.12 = window + ~6x error;
// FULLTH 0.30 >= AMBIG + 2*error with 4x slack.
#define AMBIG_S  0.12f
#define FULLTH_S 0.30f

#define TC 64                 // codes per LDS tile
#define NT (KCODES / TC)      // 16 tiles
#define PAIR_BLOCKS 192
#define GATHER_BLOCKS 1024
#define GATHER_ITERS 8        // 1024*256*8 = 2M float4 = N_ROWS*DIM/4

typedef __attribute__((ext_vector_type(8))) _Float16 f16x8;
typedef __attribute__((ext_vector_type(4))) float f32x4;
typedef unsigned short u16;

// ws layout (bytes):
//   [0, 4096)            sen float[K]
//   [4096, 8192)         hist uint[K]
//   [8192, 8196)         uint pair_count
//   [8196, 8200)         uint full_count
//   [8448, 270592)       pairlist uint2[32768]  {row, c1<<16|c2}
//   [270592, 401664)     fulllist uint[32768]
//   [401664, 925952)     e16 u16[262144]  (fp16 of -1024*e, row-major [code][dim])
//   [925952, 934144)     partials double[1024]  (per-block loss sums)

__device__ inline u16 f16bits(_Float16 h) {
    union { _Float16 h; u16 u; } x; x.h = h; return x.u;
}

__device__ inline bool lexless(float av, int ai, float bv, int bi) {
    return av < bv || (av == bv && ai < bi);
}

typedef __attribute__((address_space(3))) unsigned int as3_uint;
typedef __attribute__((address_space(1))) const unsigned int as1_uint;
__device__ inline void gload_lds16(const void* g, void* l) {
    __builtin_amdgcn_global_load_lds((as1_uint*)g, (as3_uint*)l, 16, 0, 0);
}

// fused: init(hist/counters) + accurate ||e||^2 + e16 = fp16(-1024*e).
__global__ __launch_bounds__(256) void vq_prep_cb(const float* __restrict__ cb,
                                                  float* __restrict__ sen,
                                                  u16* __restrict__ e16,
                                                  unsigned* __restrict__ hist,
                                                  unsigned* __restrict__ pcnt,
                                                  unsigned* __restrict__ fcnt) {
    int b = blockIdx.x, t = threadIdx.x;
    if (b < 4) {
        hist[b * 256 + t] = 0u;
        if (b == 0 && t == 0) { *pcnt = 0u; *fcnt = 0u; }
    }
    int code = b * 4 + (t >> 6);
    int lane = t & 63;
    size_t eoff = (size_t)code * DIM + lane * 4;
    float4 v = *(const float4*)(cb + eoff);
    double s = (double)v.x * v.x + (double)v.y * v.y + (double)v.z * v.z + (double)v.w * v.w;
    #pragma unroll
    for (int off = 32; off; off >>= 1) s += __shfl_down(s, off, 64);
    if (lane == 0) sen[code] = (float)s;
    // -1024*e: exact pow2 scale in fp32, then single RNE to fp16
    ushort4 us;
    us.x = f16bits((_Float16)(-1024.0f * v.x));
    us.y = f16bits((_Float16)(-1024.0f * v.y));
    us.z = f16bits((_Float16)(-1024.0f * v.z));
    us.w = f16bits((_Float16)(-1024.0f * v.w));
    *(ushort4*)(e16 + eoff) = us;
}

// fp16 MFMA distance-argmin. 512 blocks x 4 waves x 16 rows/wave (2 blocks/CU,
// 8 waves/CU in two independent barrier groups). One MFMA per (code-tile,
// d-chunk): acc' = 512 + 512*sen - 1024*dot via biased C-init. e16 staged in
// 64-code/32KB tiles (global_load_lds, double-buffered, T2 XOR-swizzle as
// inverse-swizzled SOURCE + swizzled READ). Packed-key top-3 (min/med u32).
__global__ __launch_bounds__(256, 2) void vq_mfma(const float* __restrict__ z,
                                                  const u16* __restrict__ e16,
                                                  const float* __restrict__ sen,
                                                  float* __restrict__ idx_out,
                                                  unsigned* __restrict__ pcnt,
                                                  uint2* __restrict__ pairlist,
                                                  unsigned* __restrict__ fcnt,
                                                  unsigned* __restrict__ fulllist) {
    __shared__ char lds[2][32768];
    const int tid = threadIdx.x;
    const int wid = tid >> 6;        // 0..3
    const int lane = tid & 63;
    const int col16 = lane & 15;
    const int koct = lane >> 4;
    const int s3 = col16 & 7;
    const int rowbase = blockIdx.x * 64 + wid * 16;

    // A fragments: z rows converted fp32->fp16 in-register (RNE)
    f16x8 zf[8];
    {
        const float* zp = z + (size_t)(rowbase + col16) * DIM + koct * 8;
        #pragma unroll
        for (int dc = 0; dc < 8; ++dc) {
            float4 f0 = *(const float4*)(zp + dc * 32);
            float4 f1 = *(const float4*)(zp + dc * 32 + 4);
            f16x8 h;
            h[0] = (_Float16)f0.x; h[1] = (_Float16)f0.y;
            h[2] = (_Float16)f0.z; h[3] = (_Float16)f0.w;
            h[4] = (_Float16)f1.x; h[5] = (_Float16)f1.y;
            h[6] = (_Float16)f1.z; h[7] = (_Float16)f1.w;
            zf[dc] = h;
        }
    }

    unsigned k1[4], k2[4], k3[4];
    #pragma unroll
    for (int r = 0; r < 4; ++r) { k1[r] = k2[r] = k3[r] = 0xFFFFFFFFu; }

    // stage 64-code tile tt (32KB = 2048 x 16B chunks) into buffer b
    auto STAGE = [&](int tt, int b) {
        #pragma unroll
        for (int r = 0; r < 8; ++r) {
            int p = r * 256 + tid;
            int src = p ^ ((p >> 5) & 7);          // inverse swizzle (involution)
            const char* sp = (const char*)e16 + (size_t)tt * 32768 + src * 16;
            gload_lds16(sp, &lds[b][p * 16]);
        }
    };

    STAGE(0, 0);
    __syncthreads();

    for (int tt = 0; tt < NT; ++tt) {
        if (tt + 1 < NT) STAGE(tt + 1, (tt + 1) & 1);
        const char* bb = lds[tt & 1];
        f32x4 acc[4];
        #pragma unroll
        for (int ct = 0; ct < 4; ++ct) {
            float sv = sen[tt * TC + ct * 16 + col16];
            float b0 = fmaf(512.0f, sv, 512.0f);   // positive-bias C init
            acc[ct] = (f32x4){b0, b0, b0, b0};
        }
        #pragma unroll
        for (int dc = 0; dc < 8; ++dc) {
            int swcol = ((dc * 4 + koct) ^ s3) * 16;
            #pragma unroll
            for (int ct = 0; ct < 4; ++ct) {
                int off = (ct * 16 + col16) * 512 + swcol;
                f16x8 bv = *(const f16x8*)(bb + off);
                acc[ct] = __builtin_amdgcn_mfma_f32_16x16x32_f16(zf[dc], bv, acc[ct], 0, 0, 0);
            }
        }
        #pragma unroll
        for (int ct = 0; ct < 4; ++ct) {
            const unsigned lidx = (unsigned)(tt * 4 + ct);
            #pragma unroll
            for (int r = 0; r < 4; ++r) {
                float s = acc[ct][r];
                unsigned key = (__float_as_uint(s) & 0xFFFFFFC0u) | lidx;
                unsigned o1 = k1[r];
                k1[r] = min(o1, key);                       // new min
                k3[r] = min(k3[r], max(k2[r], key));        // new 3rd (old k2)
                k2[r] = min(max(key, o1), k2[r]);           // med(o1,k2,key)
            }
        }
        __syncthreads();
    }

    #pragma unroll
    for (int r = 0; r < 4; ++r) {
        float a1 = __uint_as_float(k1[r] & 0xFFFFFFC0u);
        float a2 = __uint_as_float(k2[r] & 0xFFFFFFC0u);
        float a3 = __uint_as_float(k3[r] & 0xFFFFFFC0u);
        int l1 = (int)(k1[r] & 63u), l2 = (int)(k2[r] & 63u), l3 = (int)(k3[r] & 63u);
        int b1 = (l1 >> 2) * TC + (l1 & 3) * 16 + col16;
        int b2 = (l2 >> 2) * TC + (l2 & 3) * 16 + col16;
        int b3 = (l3 >> 2) * TC + (l3 & 3) * 16 + col16;
        #pragma unroll
        for (int m = 1; m < 16; m <<= 1) {
            float o1 = __shfl_xor(a1, m, 64), o2 = __shfl_xor(a2, m, 64), o3 = __shfl_xor(a3, m, 64);
            int p1 = __shfl_xor(b1, m, 64), p2 = __shfl_xor(b2, m, 64), p3 = __shfl_xor(b3, m, 64);
            #pragma unroll
            for (int k = 0; k < 3; ++k) {
                float ov = (k == 0) ? o1 : (k == 1) ? o2 : o3;
                int oi = (k == 0) ? p1 : (k == 1) ? p2 : p3;
                if (lexless(ov, oi, a1, b1)) {
                    a3 = a2; b3 = b2; a2 = a1; b2 = b1; a1 = ov; b1 = oi;
                } else if (lexless(ov, oi, a2, b2)) {
                    a3 = a2; b3 = b2; a2 = ov; b2 = oi;
                } else if (lexless(ov, oi, a3, b3)) {
                    a3 = ov; b3 = oi;
                }
            }
        }
        if (col16 == 0) {
            int row = rowbase + koct * 4 + r;
            idx_out[row] = (float)b1;
            if (a2 - a1 < AMBIG_S) {
                if (a3 - a1 < FULLTH_S) {
                    unsigned slot = atomicAdd(fcnt, 1u);
                    fulllist[slot] = (unsigned)row;
                } else {
                    unsigned slot = atomicAdd(pcnt, 1u);
                    pairlist[slot] = make_uint2((unsigned)row,
                                                ((unsigned)b1 << 16) | (unsigned)b2);
                }
            }
        }
    }
}

// np-pairwise ||z||^2 for one row, replicated in every 16-lane group of a wave.
__device__ inline float szn_wave(const float* __restrict__ zrow, int lane) {
    int sub = lane & 15;
    int hb = sub >> 3;
    int j = sub & 7;
    const float* a = zrow + hb * 128 + j;
    float v0 = a[0];
    float c = __fmul_rn(v0, v0);
    #pragma unroll
    for (int i = 1; i < 16; ++i) {
        float w = a[8 * i];
        c = __fadd_rn(c, __fmul_rn(w, w));
    }
    float p;
    p = __shfl_xor(c, 1, 64); c = __fadd_rn(c, p);
    p = __shfl_xor(c, 2, 64); c = __fadd_rn(c, p);
    p = __shfl_xor(c, 4, 64); c = __fadd_rn(c, p);
    p = __shfl_xor(c, 8, 64); c = __fadd_rn(c, p);
    return c;
}

// fused fix kernel: wave-per-row pair rescore (blocks [0,192)) +
// block-per-row full np-exact rescan (blocks [192,256)).
__global__ __launch_bounds__(256) void vq_fix(const float* __restrict__ z,
                                              const float* __restrict__ cb,
                                              const float* __restrict__ sen,
                                              const unsigned* __restrict__ pcnt,
                                              const uint2* __restrict__ pairlist,
                                              const unsigned* __restrict__ fcnt,
                                              const unsigned* __restrict__ fulllist,
                                              float* __restrict__ idx_out) {
    if (blockIdx.x < PAIR_BLOCKS) {
        int wave = blockIdx.x * 4 + (threadIdx.x >> 6);
        int lane = threadIdx.x & 63;
        int half = lane >> 5, s5 = lane & 31;
        int n = (int)*pcnt;
        for (int w = wave; w < n; w += PAIR_BLOCKS * 4) {
            uint2 pr = pairlist[w];
            int row = (int)pr.x;
            int c1 = (int)(pr.y >> 16), c2 = (int)(pr.y & 0xffffu);
            const float* zrow = z + (size_t)row * DIM;
            float sz = szn_wave(zrow, lane);
            int c = half ? c2 : c1;
            const float* zp = zrow + s5 * 8;
            const float* ep = cb + (size_t)c * DIM + s5 * 8;
            float4 za = *(const float4*)zp, zb = *(const float4*)(zp + 4);
            float4 ea = *(const float4*)ep, eb = *(const float4*)(ep + 4);
            double acc = (double)ea.x * za.x + (double)ea.y * za.y
                       + (double)ea.z * za.z + (double)ea.w * za.w
                       + (double)eb.x * zb.x + (double)eb.y * zb.y
                       + (double)eb.z * zb.z + (double)eb.w * zb.w;
            #pragma unroll
            for (int m = 1; m < 32; m <<= 1) acc += __shfl_xor(acc, m, 64);
            double d2 = __shfl(acc, 32, 64);            // lane0 reads half-1 dot
            if (lane == 0) {
                float A1 = __fadd_rn(sz, sen[c1]);
                float dref1 = __fmaf_rn(-2.0f, (float)acc, A1);
                float A2 = __fadd_rn(sz, sen[c2]);
                float dref2 = __fmaf_rn(-2.0f, (float)d2, A2);
                int win = lexless(dref1, c1, dref2, c2) ? c1 : c2;
                idx_out[row] = (float)win;
            }
        }
    } else {
        __shared__ float zrow[DIM];
        __shared__ float sz_s;
        __shared__ float rv[256];
        __shared__ int ri[256];
        int t = threadIdx.x;
        int n = (int)*fcnt;
        for (int w = blockIdx.x - PAIR_BLOCKS; w < n; w += 256 - PAIR_BLOCKS) {
            int row = (int)fulllist[w];
            zrow[t] = z[(size_t)row * DIM + t];
            __syncthreads();
            if (t < 64) {
                float sz = szn_wave(zrow, t);
                if (t == 0) sz_s = sz;
            }
            __syncthreads();
            float sz = sz_s;
            float bv = 3.4e38f;
            int bi = 0x7fffffff;
            #pragma unroll
            for (int cc = 0; cc < 4; ++cc) {
                int c = t * 4 + cc;
                const float* e = cb + (size_t)c * DIM;
                double dot = 0.0;
                for (int d = 0; d < DIM; d += 4) {
                    float4 ev = *(const float4*)(e + d);
                    dot += (double)ev.x * zrow[d + 0] + (double)ev.y * zrow[d + 1]
                         + (double)ev.z * zrow[d + 2] + (double)ev.w * zrow[d + 3];
                }
                float dotx = (float)dot;
                float A = __fadd_rn(sz, sen[c]);
                float dref = __fmaf_rn(-2.0f, dotx, A);
                if (dref < bv) { bv = dref; bi = c; }   // ascending c: first-min
            }
            rv[t] = bv; ri[t] = bi;
            __syncthreads();
            for (int s = 128; s; s >>= 1) {
                if (t < s) {
                    if (lexless(rv[t + s], ri[t + s], rv[t], ri[t])) {
                        rv[t] = rv[t + s]; ri[t] = ri[t + s];
                    }
                }
                __syncthreads();
            }
            if (t == 0) idx_out[row] = (float)ri[0];
            __syncthreads();
        }
    }
}

// quantized_ste + commitment loss + histogram. Per-block loss partials
// (no same-address atomics); 1024 blocks x 256 thr x 8 float4 iters.
__global__ __launch_bounds__(256) void vq_gather(const float* __restrict__ z,
                                                 const float* __restrict__ cb,
                                                 const float* __restrict__ idxf,
                                                 float* __restrict__ qout,
                                                 unsigned* __restrict__ hist,
                                                 double* __restrict__ partials) {
    const int tid = threadIdx.x;
    double lacc = 0.0;
    #pragma unroll
    for (int it = 0; it < GATHER_ITERS; ++it) {
        int g = it * (GATHER_BLOCKS * 256) + blockIdx.x * 256 + tid;
        int row = g >> 6, c4 = g & 63;
        int idx = (int)idxf[row];
        if (c4 == 0) atomicAdd(&hist[idx], 1u);
        float4 zv = *(const float4*)(z + (size_t)g * 4);
        float4 qv = *(const float4*)(cb + (size_t)idx * DIM + c4 * 4);
        float dx = qv.x - zv.x, dy = qv.y - zv.y, dz = qv.z - zv.z, dw = qv.w - zv.w;
        float4 o;
        o.x = zv.x + dx; o.y = zv.y + dy; o.z = zv.z + dz; o.w = zv.w + dw;
        *(float4*)(qout + (size_t)g * 4) = o;
        lacc += (double)(dx * dx + dy * dy + dz * dz + dw * dw);
    }
    #pragma unroll
    for (int off = 32; off; off >>= 1) lacc += __shfl_down(lacc, off, 64);
    __shared__ double wsum[4];
    int lane = tid & 63, wv = tid >> 6;
    if (lane == 0) wsum[wv] = lacc;
    __syncthreads();
    if (tid == 0)
        partials[blockIdx.x] = (wsum[0] + wsum[1]) + (wsum[2] + wsum[3]);
}

// reduce 1024 loss partials (double) + hist entropy -> 3 scalars
__global__ __launch_bounds__(1024) void vq_finalize(const unsigned* __restrict__ hist,
                                                    const double* __restrict__ partials,
                                                    float* __restrict__ out) {
    __shared__ float red[1024];
    __shared__ double redd[1024];
    int t = threadIdx.x;
    float p = (float)hist[t] * (1.0f / (float)N_ROWS);
    red[t] = p * logf(p + 1e-10f);
    redd[t] = partials[t];
    __syncthreads();
    for (int s = 512; s; s >>= 1) {
        if (t < s) { red[t] += red[t + s]; redd[t] += redd[t + s]; }
        __syncthreads();
    }
    if (t == 0) {
        out[ZERO_OFF] = 0.0f;
        out[LOSS_OFF] = (float)(0.25 * redd[0] / (double)Q_N);
        out[PERP_OFF] = expf(-red[0]);
    }
}

extern "C" void kernel_launch(void* const* d_in, const int* in_sizes, int n_in,
                              void* d_out, int out_size, void* d_ws, size_t ws_size,
                              hipStream_t stream) {
    const float* z = (const float*)d_in[0];
    const float* cb = (const float*)d_in[1];
    float* out = (float*)d_out;

    float* sen = (float*)d_ws;
    unsigned* hist = (unsigned*)((char*)d_ws + 4096);
    unsigned* pcnt = (unsigned*)((char*)d_ws + 8192);
    unsigned* fcnt = (unsigned*)((char*)d_ws + 8196);
    uint2* pairlist = (uint2*)((char*)d_ws + 8448);
    unsigned* fulllist = (unsigned*)((char*)d_ws + 270592);
    u16* e16 = (u16*)((char*)d_ws + 401664);
    double* partials = (double*)((char*)d_ws + 925952);

    vq_prep_cb<<<KCODES / 4, 256, 0, stream>>>(cb, sen, e16, hist, pcnt, fcnt);
    vq_mfma<<<N_ROWS / 64, 256, 0, stream>>>(z, e16, sen,
                                             out + IDX_OFF, pcnt, pairlist, fcnt, fulllist);
    vq_fix<<<256, 256, 0, stream>>>(z, cb, sen, pcnt, pairlist, fcnt, fulllist, out + IDX_OFF);
    vq_gather<<<GATHER_BLOCKS, 256, 0, stream>>>(z, cb, out + IDX_OFF, out, hist, partials);
    vq_finalize<<<1, 1024, 0, stream>>>(hist, partials, out);
}

// Round 13
// 129.469 us; speedup vs baseline: 1.5206x; 1.5206x over previous
//
#include <hip/hip_runtime.h>

#define N_ROWS 32768
#define DIM 256
#define KCODES 1024

#define Q_N (N_ROWS * DIM)          // 8388608
#define IDX_OFF Q_N                 // 8388608
#define ZERO_OFF (Q_N + N_ROWS)     // 8421376
#define LOSS_OFF (ZERO_OFF + 1)
#define PERP_OFF (ZERO_OFF + 2)

// Scaled-acc units: acc' = 512 + 512*sen - 1024*dot (=1024*(score/2)+512).
// Required window T = np-flip window (0.031) + 2*fast-path error (~0.027)
// ~= 0.085. AMBIG_S = 0.12 covers with 1.4x slack; used for BOTH the pair
// trigger (a2) and the full trigger (a3) -- pair is sufficient iff a3 >= T.
#define AMBIG_S  0.12f

#define TC 64                 // codes per LDS tile
#define NT (KCODES / TC)      // 16 tiles
#define FIX_GRID 1024
#define PAIR_BLOCKS 768       // full-scan blocks = FIX_GRID - PAIR_BLOCKS = 256
#define GATHER_BLOCKS 1024
#define GATHER_ITERS 8        // 1024*256*8 = 2M float4 = N_ROWS*DIM/4

typedef __attribute__((ext_vector_type(8))) _Float16 f16x8;
typedef __attribute__((ext_vector_type(4))) float f32x4;
typedef unsigned short u16;

// ws layout (bytes):
//   [0, 4096)            sen float[K]
//   [4096, 8192)         hist uint[K]
//   [8192, 8196)         uint pair_count
//   [8196, 8200)         uint full_count
//   [8448, 270592)       pairlist uint2[32768]  {row, c1<<16|c2}
//   [270592, 401664)     fulllist uint[32768]
//   [401664, 925952)     e16 u16[262144]  (fp16 of -1024*e, row-major)
//   [925952, 934144)     partials double[1024]  (per-block loss sums)

__device__ inline u16 f16bits(_Float16 h) {
    union { _Float16 h; u16 u; } x; x.h = h; return x.u;
}

__device__ inline bool lexless(float av, int ai, float bv, int bi) {
    return av < bv || (av == bv && ai < bi);
}

typedef __attribute__((address_space(3))) unsigned int as3_uint;
typedef __attribute__((address_space(1))) const unsigned int as1_uint;
__device__ inline void gload_lds16(const void* g, void* l) {
    __builtin_amdgcn_global_load_lds((as1_uint*)g, (as3_uint*)l, 16, 0, 0);
}

// fused: init(hist/counters) + accurate ||e||^2 + e16 = fp16(-1024*e).
__global__ __launch_bounds__(256) void vq_prep_cb(const float* __restrict__ cb,
                                                  float* __restrict__ sen,
                                                  u16* __restrict__ e16,
                                                  unsigned* __restrict__ hist,
                                                  unsigned* __restrict__ pcnt,
                                                  unsigned* __restrict__ fcnt) {
    int b = blockIdx.x, t = threadIdx.x;
    if (b < 4) {
        hist[b * 256 + t] = 0u;
        if (b == 0 && t == 0) { *pcnt = 0u; *fcnt = 0u; }
    }
    int code = b * 4 + (t >> 6);
    int lane = t & 63;
    size_t eoff = (size_t)code * DIM + lane * 4;
    float4 v = *(const float4*)(cb + eoff);
    double s = (double)v.x * v.x + (double)v.y * v.y + (double)v.z * v.z + (double)v.w * v.w;
    #pragma unroll
    for (int off = 32; off; off >>= 1) s += __shfl_down(s, off, 64);
    if (lane == 0) sen[code] = (float)s;
    ushort4 us;
    us.x = f16bits((_Float16)(-1024.0f * v.x));
    us.y = f16bits((_Float16)(-1024.0f * v.y));
    us.z = f16bits((_Float16)(-1024.0f * v.z));
    us.w = f16bits((_Float16)(-1024.0f * v.w));
    *(ushort4*)(e16 + eoff) = us;
}

// fp16 MFMA distance-argmin (validated round 12). 512 blocks x 4 waves x
// 16 rows/wave, 2 blocks/CU. One MFMA per (code16, d-chunk); biased C-init.
// e16 staged in 64-code/32KB tiles, double-buffered, T2 XOR-swizzle.
// Packed-key top-3; classification: a2 gap -> pair, a3 gap -> full.
__global__ __launch_bounds__(256, 2) void vq_mfma(const float* __restrict__ z,
                                                  const u16* __restrict__ e16,
                                                  const float* __restrict__ sen,
                                                  float* __restrict__ idx_out,
                                                  unsigned* __restrict__ pcnt,
                                                  uint2* __restrict__ pairlist,
                                                  unsigned* __restrict__ fcnt,
                                                  unsigned* __restrict__ fulllist) {
    __shared__ char lds[2][32768];
    const int tid = threadIdx.x;
    const int wid = tid >> 6;        // 0..3
    const int lane = tid & 63;
    const int col16 = lane & 15;
    const int koct = lane >> 4;
    const int s3 = col16 & 7;
    const int rowbase = blockIdx.x * 64 + wid * 16;

    f16x8 zf[8];
    {
        const float* zp = z + (size_t)(rowbase + col16) * DIM + koct * 8;
        #pragma unroll
        for (int dc = 0; dc < 8; ++dc) {
            float4 f0 = *(const float4*)(zp + dc * 32);
            float4 f1 = *(const float4*)(zp + dc * 32 + 4);
            f16x8 h;
            h[0] = (_Float16)f0.x; h[1] = (_Float16)f0.y;
            h[2] = (_Float16)f0.z; h[3] = (_Float16)f0.w;
            h[4] = (_Float16)f1.x; h[5] = (_Float16)f1.y;
            h[6] = (_Float16)f1.z; h[7] = (_Float16)f1.w;
            zf[dc] = h;
        }
    }

    unsigned k1[4], k2[4], k3[4];
    #pragma unroll
    for (int r = 0; r < 4; ++r) { k1[r] = k2[r] = k3[r] = 0xFFFFFFFFu; }

    auto STAGE = [&](int tt, int b) {
        #pragma unroll
        for (int r = 0; r < 8; ++r) {
            int p = r * 256 + tid;
            int src = p ^ ((p >> 5) & 7);          // inverse swizzle (involution)
            const char* sp = (const char*)e16 + (size_t)tt * 32768 + src * 16;
            gload_lds16(sp, &lds[b][p * 16]);
        }
    };

    STAGE(0, 0);
    __syncthreads();

    for (int tt = 0; tt < NT; ++tt) {
        if (tt + 1 < NT) STAGE(tt + 1, (tt + 1) & 1);
        const char* bb = lds[tt & 1];
        f32x4 acc[4];
        #pragma unroll
        for (int ct = 0; ct < 4; ++ct) {
            float sv = sen[tt * TC + ct * 16 + col16];
            float b0 = fmaf(512.0f, sv, 512.0f);   // positive-bias C init
            acc[ct] = (f32x4){b0, b0, b0, b0};
        }
        #pragma unroll
        for (int dc = 0; dc < 8; ++dc) {
            int swcol = ((dc * 4 + koct) ^ s3) * 16;
            #pragma unroll
            for (int ct = 0; ct < 4; ++ct) {
                int off = (ct * 16 + col16) * 512 + swcol;
                f16x8 bv = *(const f16x8*)(bb + off);
                acc[ct] = __builtin_amdgcn_mfma_f32_16x16x32_f16(zf[dc], bv, acc[ct], 0, 0, 0);
            }
        }
        #pragma unroll
        for (int ct = 0; ct < 4; ++ct) {
            const unsigned lidx = (unsigned)(tt * 4 + ct);
            #pragma unroll
            for (int r = 0; r < 4; ++r) {
                float s = acc[ct][r];
                unsigned key = (__float_as_uint(s) & 0xFFFFFFC0u) | lidx;
                unsigned o1 = k1[r];
                k1[r] = min(o1, key);                       // new min
                k3[r] = min(k3[r], max(k2[r], key));        // new 3rd (old k2)
                k2[r] = min(max(key, o1), k2[r]);           // med(o1,k2,key)
            }
        }
        __syncthreads();
    }

    #pragma unroll
    for (int r = 0; r < 4; ++r) {
        float a1 = __uint_as_float(k1[r] & 0xFFFFFFC0u);
        float a2 = __uint_as_float(k2[r] & 0xFFFFFFC0u);
        float a3 = __uint_as_float(k3[r] & 0xFFFFFFC0u);
        int l1 = (int)(k1[r] & 63u), l2 = (int)(k2[r] & 63u), l3 = (int)(k3[r] & 63u);
        int b1 = (l1 >> 2) * TC + (l1 & 3) * 16 + col16;
        int b2 = (l2 >> 2) * TC + (l2 & 3) * 16 + col16;
        int b3 = (l3 >> 2) * TC + (l3 & 3) * 16 + col16;
        #pragma unroll
        for (int m = 1; m < 16; m <<= 1) {
            float o1 = __shfl_xor(a1, m, 64), o2 = __shfl_xor(a2, m, 64), o3 = __shfl_xor(a3, m, 64);
            int p1 = __shfl_xor(b1, m, 64), p2 = __shfl_xor(b2, m, 64), p3 = __shfl_xor(b3, m, 64);
            #pragma unroll
            for (int k = 0; k < 3; ++k) {
                float ov = (k == 0) ? o1 : (k == 1) ? o2 : o3;
                int oi = (k == 0) ? p1 : (k == 1) ? p2 : p3;
                if (lexless(ov, oi, a1, b1)) {
                    a3 = a2; b3 = b2; a2 = a1; b2 = b1; a1 = ov; b1 = oi;
                } else if (lexless(ov, oi, a2, b2)) {
                    a3 = a2; b3 = b2; a2 = ov; b2 = oi;
                } else if (lexless(ov, oi, a3, b3)) {
                    a3 = ov; b3 = oi;
                }
            }
        }
        if (col16 == 0) {
            int row = rowbase + koct * 4 + r;
            idx_out[row] = (float)b1;
            if (a2 - a1 < AMBIG_S) {
                if (a3 - a1 < AMBIG_S) {               // >=2 contenders near a1
                    unsigned slot = atomicAdd(fcnt, 1u);
                    fulllist[slot] = (unsigned)row;
                } else {                               // exactly one contender
                    unsigned slot = atomicAdd(pcnt, 1u);
                    pairlist[slot] = make_uint2((unsigned)row,
                                                ((unsigned)b1 << 16) | (unsigned)b2);
                }
            }
        }
    }
}

// np-pairwise ||z||^2, replicated in every 16-lane group (pointer may be LDS).
__device__ inline float szn_wave(const float* __restrict__ zrow, int lane) {
    int sub = lane & 15;
    int hb = sub >> 3;
    int j = sub & 7;
    const float* a = zrow + hb * 128 + j;
    float v0 = a[0];
    float c = __fmul_rn(v0, v0);
    #pragma unroll
    for (int i = 1; i < 16; ++i) {
        float w = a[8 * i];
        c = __fadd_rn(c, __fmul_rn(w, w));
    }
    float p;
    p = __shfl_xor(c, 1, 64); c = __fadd_rn(c, p);
    p = __shfl_xor(c, 2, 64); c = __fadd_rn(c, p);
    p = __shfl_xor(c, 4, 64); c = __fadd_rn(c, p);
    p = __shfl_xor(c, 8, 64); c = __fadd_rn(c, p);
    return c;
}

// fused fix. Blocks [0,768): wave-per-row pair rescore (3072 waves -> ~1 row
// each). Blocks [768,1024): block-per-row full np-exact rescan, COALESCED:
// 4 waves x 4 sixteen-lane groups = 16 code-dots per pass, 64 passes; each
// group's lanes read contiguous 64B slices of one code row; 16-deep fp64
// chain + 4-step shfl reduce; passes independent (ILP).
__global__ __launch_bounds__(256) void vq_fix(const float* __restrict__ z,
                                              const float* __restrict__ cb,
                                              const float* __restrict__ sen,
                                              const unsigned* __restrict__ pcnt,
                                              const uint2* __restrict__ pairlist,
                                              const unsigned* __restrict__ fcnt,
                                              const unsigned* __restrict__ fulllist,
                                              float* __restrict__ idx_out) {
    if (blockIdx.x < PAIR_BLOCKS) {
        int wave = blockIdx.x * 4 + (threadIdx.x >> 6);
        int lane = threadIdx.x & 63;
        int half = lane >> 5, s5 = lane & 31;
        int n = (int)*pcnt;
        for (int w = wave; w < n; w += PAIR_BLOCKS * 4) {
            uint2 pr = pairlist[w];
            int row = (int)pr.x;
            int c1 = (int)(pr.y >> 16), c2 = (int)(pr.y & 0xffffu);
            const float* zrow = z + (size_t)row * DIM;
            float sz = szn_wave(zrow, lane);
            int c = half ? c2 : c1;
            const float* zp = zrow + s5 * 8;
            const float* ep = cb + (size_t)c * DIM + s5 * 8;
            float4 za = *(const float4*)zp, zb = *(const float4*)(zp + 4);
            float4 ea = *(const float4*)ep, eb = *(const float4*)(ep + 4);
            double acc = (double)ea.x * za.x + (double)ea.y * za.y
                       + (double)ea.z * za.z + (double)ea.w * za.w
                       + (double)eb.x * zb.x + (double)eb.y * zb.y
                       + (double)eb.z * zb.z + (double)eb.w * zb.w;
            #pragma unroll
            for (int m = 1; m < 32; m <<= 1) acc += __shfl_xor(acc, m, 64);
            double d2 = __shfl(acc, 32, 64);            // lane0 reads half-1 dot
            if (lane == 0) {
                float A1 = __fadd_rn(sz, sen[c1]);
                float dref1 = __fmaf_rn(-2.0f, (float)acc, A1);
                float A2 = __fadd_rn(sz, sen[c2]);
                float dref2 = __fmaf_rn(-2.0f, (float)d2, A2);
                int win = lexless(dref1, c1, dref2, c2) ? c1 : c2;
                idx_out[row] = (float)win;
            }
        }
    } else {
        __shared__ float zrow[DIM];
        __shared__ float szs;
        __shared__ float fv[16];
        __shared__ int   fi[16];
        const int t = threadIdx.x;
        const int lane = t & 63, wid = t >> 6;     // 4 waves
        const int grp = lane >> 4, sub = lane & 15;
        int n = (int)*fcnt;
        for (int w = (int)blockIdx.x - PAIR_BLOCKS; w < n; w += FIX_GRID - PAIR_BLOCKS) {
            int row = (int)fulllist[w];
            zrow[t] = z[(size_t)row * DIM + t];
            __syncthreads();
            if (t < 64) {
                float s = szn_wave(zrow, t);
                if (t == 0) szs = s;
            }
            __syncthreads();
            const float sz = szs;
            float bv = 3.4e38f;
            int bi = 0x7fffffff;
            #pragma unroll 2
            for (int pass = 0; pass < 64; ++pass) {
                int c = pass * 16 + wid * 4 + grp;     // ascending per group
                const float* e = cb + (size_t)c * DIM + sub * 16;
                const float* zz = &zrow[sub * 16];
                double dot = 0.0;
                #pragma unroll
                for (int q4 = 0; q4 < 4; ++q4) {
                    float4 ev = *(const float4*)(e + q4 * 4);
                    dot += (double)ev.x * zz[q4 * 4 + 0] + (double)ev.y * zz[q4 * 4 + 1]
                         + (double)ev.z * zz[q4 * 4 + 2] + (double)ev.w * zz[q4 * 4 + 3];
                }
                #pragma unroll
                for (int m = 1; m < 16; m <<= 1) dot += __shfl_xor(dot, m, 64);
                if (sub == 0) {
                    float A = __fadd_rn(sz, sen[c]);
                    float dref = __fmaf_rn(-2.0f, (float)dot, A);
                    if (dref < bv) { bv = dref; bi = c; }   // strict <: first-min
                }
            }
            if (sub == 0) { fv[wid * 4 + grp] = bv; fi[wid * 4 + grp] = bi; }
            __syncthreads();
            if (t == 0) {
                float v = fv[0]; int i = fi[0];
                #pragma unroll
                for (int k = 1; k < 16; ++k)
                    if (lexless(fv[k], fi[k], v, i)) { v = fv[k]; i = fi[k]; }
                idx_out[row] = (float)i;
            }
            __syncthreads();
        }
    }
}

// quantized_ste + commitment loss + histogram. Per-block loss partials
// (no same-address atomics); 1024 blocks x 256 thr x 8 float4 iters.
__global__ __launch_bounds__(256) void vq_gather(const float* __restrict__ z,
                                                 const float* __restrict__ cb,
                                                 const float* __restrict__ idxf,
                                                 float* __restrict__ qout,
                                                 unsigned* __restrict__ hist,
                                                 double* __restrict__ partials) {
    const int tid = threadIdx.x;
    double lacc = 0.0;
    #pragma unroll
    for (int it = 0; it < GATHER_ITERS; ++it) {
        int g = it * (GATHER_BLOCKS * 256) + blockIdx.x * 256 + tid;
        int row = g >> 6, c4 = g & 63;
        int idx = (int)idxf[row];
        if (c4 == 0) atomicAdd(&hist[idx], 1u);
        float4 zv = *(const float4*)(z + (size_t)g * 4);
        float4 qv = *(const float4*)(cb + (size_t)idx * DIM + c4 * 4);
        float dx = qv.x - zv.x, dy = qv.y - zv.y, dz = qv.z - zv.z, dw = qv.w - zv.w;
        float4 o;
        o.x = zv.x + dx; o.y = zv.y + dy; o.z = zv.z + dz; o.w = zv.w + dw;
        *(float4*)(qout + (size_t)g * 4) = o;
        lacc += (double)(dx * dx + dy * dy + dz * dz + dw * dw);
    }
    #pragma unroll
    for (int off = 32; off; off >>= 1) lacc += __shfl_down(lacc, off, 64);
    __shared__ double wsum[4];
    int lane = tid & 63, wv = tid >> 6;
    if (lane == 0) wsum[wv] = lacc;
    __syncthreads();
    if (tid == 0)
        partials[blockIdx.x] = (wsum[0] + wsum[1]) + (wsum[2] + wsum[3]);
}

// reduce 1024 loss partials (double) + hist entropy -> 3 scalars
__global__ __launch_bounds__(1024) void vq_finalize(const unsigned* __restrict__ hist,
                                                    const double* __restrict__ partials,
                                                    float* __restrict__ out) {
    __shared__ float red[1024];
    __shared__ double redd[1024];
    int t = threadIdx.x;
    float p = (float)hist[t] * (1.0f / (float)N_ROWS);
    red[t] = p * logf(p + 1e-10f);
    redd[t] = partials[t];
    __syncthreads();
    for (int s = 512; s; s >>= 1) {
        if (t < s) { red[t] += red[t + s]; redd[t] += redd[t + s]; }
        __syncthreads();
    }
    if (t == 0) {
        out[ZERO_OFF] = 0.0f;
        out[LOSS_OFF] = (float)(0.25 * redd[0] / (double)Q_N);
        out[PERP_OFF] = expf(-red[0]);
    }
}

extern "C" void kernel_launch(void* const* d_in, const int* in_sizes, int n_in,
                              void* d_out, int out_size, void* d_ws, size_t ws_size,
                              hipStream_t stream) {
    const float* z = (const float*)d_in[0];
    const float* cb = (const float*)d_in[1];
    float* out = (float*)d_out;

    float* sen = (float*)d_ws;
    unsigned* hist = (unsigned*)((char*)d_ws + 4096);
    unsigned* pcnt = (unsigned*)((char*)d_ws + 8192);
    unsigned* fcnt = (unsigned*)((char*)d_ws + 8196);
    uint2* pairlist = (uint2*)((char*)d_ws + 8448);
    unsigned* fulllist = (unsigned*)((char*)d_ws + 270592);
    u16* e16 = (u16*)((char*)d_ws + 401664);
    double* partials = (double*)((char*)d_ws + 925952);

    vq_prep_cb<<<KCODES / 4, 256, 0, stream>>>(cb, sen, e16, hist, pcnt, fcnt);
    vq_mfma<<<N_ROWS / 64, 256, 0, stream>>>(z, e16, sen,
                                             out + IDX_OFF, pcnt, pairlist, fcnt, fulllist);
    vq_fix<<<FIX_GRID, 256, 0, stream>>>(z, cb, sen, pcnt, pairlist, fcnt, fulllist, out + IDX_OFF);
    vq_gather<<<GATHER_BLOCKS, 256, 0, stream>>>(z, cb, out + IDX_OFF, out, hist, partials);
    vq_finalize<<<1, 1024, 0, stream>>>(hist, partials, out);
}

// Round 14
// 103.296 us; speedup vs baseline: 1.9059x; 1.2534x over previous
//
#include <hip/hip_runtime.h>

#define N_ROWS 32768
#define DIM 256
#define KCODES 1024

#define Q_N (N_ROWS * DIM)          // 8388608
#define IDX_OFF Q_N                 // 8388608
#define ZERO_OFF (Q_N + N_ROWS)     // 8421376
#define LOSS_OFF (ZERO_OFF + 1)
#define PERP_OFF (ZERO_OFF + 2)

// Scaled-acc units: acc' = 512 + 512*sen - 1024*dot (=1024*(score/2)+512).
// Required window T = np-flip window (0.031) + 2*fast-path error (~0.027)
// ~= 0.085. AMBIG_S = 0.12 covers with 1.4x slack (pair AND full triggers).
#define AMBIG_S  0.12f

#define TC 64                 // codes per LDS tile (mfma)
#define NT (KCODES / TC)      // 16 tiles
#define PAIR_GRID 768
#define FULL_GRID 1024
#define GATHER_BLOCKS 1024
#define GATHER_ITERS 8        // 1024*256*8 = 2M float4 = N_ROWS*DIM/4

typedef __attribute__((ext_vector_type(8))) _Float16 f16x8;
typedef __attribute__((ext_vector_type(4))) float f32x4;
typedef unsigned short u16;
typedef unsigned long long u64;

// ws layout (bytes):
//   [0, 4096)            sen float[K]
//   [4096, 8192)         hist uint[K]
//   [8192, 8196)         uint pair_count
//   [8196, 8200)         uint full_count
//   [8448, 270592)       pairlist uint2[32768]  {row, c1<<16|c2}
//   [270592, 401664)     fulllist uint[32768]
//   [401664, 925952)     e16 u16[262144]  (fp16 of -1024*e, row-major)
//   [925952, 934144)     partials double[1024]  (per-block loss sums)
//   [934144, 1196288)    fullkey u64[32768]  (per-fulllist-slot packed min)

__device__ inline u16 f16bits(_Float16 h) {
    union { _Float16 h; u16 u; } x; x.h = h; return x.u;
}

__device__ inline bool lexless(float av, int ai, float bv, int bi) {
    return av < bv || (av == bv && ai < bi);
}

typedef __attribute__((address_space(3))) unsigned int as3_uint;
typedef __attribute__((address_space(1))) const unsigned int as1_uint;
__device__ inline void gload_lds16(const void* g, void* l) {
    __builtin_amdgcn_global_load_lds((as1_uint*)g, (as3_uint*)l, 16, 0, 0);
}

// fused: init(hist/counters) + accurate ||e||^2 + e16 = fp16(-1024*e).
__global__ __launch_bounds__(256) void vq_prep_cb(const float* __restrict__ cb,
                                                  float* __restrict__ sen,
                                                  u16* __restrict__ e16,
                                                  unsigned* __restrict__ hist,
                                                  unsigned* __restrict__ pcnt,
                                                  unsigned* __restrict__ fcnt) {
    int b = blockIdx.x, t = threadIdx.x;
    if (b < 4) {
        hist[b * 256 + t] = 0u;
        if (b == 0 && t == 0) { *pcnt = 0u; *fcnt = 0u; }
    }
    int code = b * 4 + (t >> 6);
    int lane = t & 63;
    size_t eoff = (size_t)code * DIM + lane * 4;
    float4 v = *(const float4*)(cb + eoff);
    double s = (double)v.x * v.x + (double)v.y * v.y + (double)v.z * v.z + (double)v.w * v.w;
    #pragma unroll
    for (int off = 32; off; off >>= 1) s += __shfl_down(s, off, 64);
    if (lane == 0) sen[code] = (float)s;
    ushort4 us;
    us.x = f16bits((_Float16)(-1024.0f * v.x));
    us.y = f16bits((_Float16)(-1024.0f * v.y));
    us.z = f16bits((_Float16)(-1024.0f * v.z));
    us.w = f16bits((_Float16)(-1024.0f * v.w));
    *(ushort4*)(e16 + eoff) = us;
}

// fp16 MFMA distance-argmin (validated round 12/13). 512 blocks x 4 waves x
// 16 rows/wave, 2 blocks/CU. Packed-key top-3; pair/full classification.
// Full-append also inits fullkey[slot] = ~0 for the fixfull atomicMin.
__global__ __launch_bounds__(256, 2) void vq_mfma(const float* __restrict__ z,
                                                  const u16* __restrict__ e16,
                                                  const float* __restrict__ sen,
                                                  float* __restrict__ idx_out,
                                                  unsigned* __restrict__ pcnt,
                                                  uint2* __restrict__ pairlist,
                                                  unsigned* __restrict__ fcnt,
                                                  unsigned* __restrict__ fulllist,
                                                  u64* __restrict__ fullkey) {
    __shared__ char lds[2][32768];
    const int tid = threadIdx.x;
    const int wid = tid >> 6;        // 0..3
    const int lane = tid & 63;
    const int col16 = lane & 15;
    const int koct = lane >> 4;
    const int s3 = col16 & 7;
    const int rowbase = blockIdx.x * 64 + wid * 16;

    f16x8 zf[8];
    {
        const float* zp = z + (size_t)(rowbase + col16) * DIM + koct * 8;
        #pragma unroll
        for (int dc = 0; dc < 8; ++dc) {
            float4 f0 = *(const float4*)(zp + dc * 32);
            float4 f1 = *(const float4*)(zp + dc * 32 + 4);
            f16x8 h;
            h[0] = (_Float16)f0.x; h[1] = (_Float16)f0.y;
            h[2] = (_Float16)f0.z; h[3] = (_Float16)f0.w;
            h[4] = (_Float16)f1.x; h[5] = (_Float16)f1.y;
            h[6] = (_Float16)f1.z; h[7] = (_Float16)f1.w;
            zf[dc] = h;
        }
    }

    unsigned k1[4], k2[4], k3[4];
    #pragma unroll
    for (int r = 0; r < 4; ++r) { k1[r] = k2[r] = k3[r] = 0xFFFFFFFFu; }

    auto STAGE = [&](int tt, int b) {
        #pragma unroll
        for (int r = 0; r < 8; ++r) {
            int p = r * 256 + tid;
            int src = p ^ ((p >> 5) & 7);          // inverse swizzle (involution)
            const char* sp = (const char*)e16 + (size_t)tt * 32768 + src * 16;
            gload_lds16(sp, &lds[b][p * 16]);
        }
    };

    STAGE(0, 0);
    __syncthreads();

    for (int tt = 0; tt < NT; ++tt) {
        if (tt + 1 < NT) STAGE(tt + 1, (tt + 1) & 1);
        const char* bb = lds[tt & 1];
        f32x4 acc[4];
        #pragma unroll
        for (int ct = 0; ct < 4; ++ct) {
            float sv = sen[tt * TC + ct * 16 + col16];
            float b0 = fmaf(512.0f, sv, 512.0f);   // positive-bias C init
            acc[ct] = (f32x4){b0, b0, b0, b0};
        }
        #pragma unroll
        for (int dc = 0; dc < 8; ++dc) {
            int swcol = ((dc * 4 + koct) ^ s3) * 16;
            #pragma unroll
            for (int ct = 0; ct < 4; ++ct) {
                int off = (ct * 16 + col16) * 512 + swcol;
                f16x8 bv = *(const f16x8*)(bb + off);
                acc[ct] = __builtin_amdgcn_mfma_f32_16x16x32_f16(zf[dc], bv, acc[ct], 0, 0, 0);
            }
        }
        #pragma unroll
        for (int ct = 0; ct < 4; ++ct) {
            const unsigned lidx = (unsigned)(tt * 4 + ct);
            #pragma unroll
            for (int r = 0; r < 4; ++r) {
                float s = acc[ct][r];
                unsigned key = (__float_as_uint(s) & 0xFFFFFFC0u) | lidx;
                unsigned o1 = k1[r];
                k1[r] = min(o1, key);                       // new min
                k3[r] = min(k3[r], max(k2[r], key));        // new 3rd (old k2)
                k2[r] = min(max(key, o1), k2[r]);           // med(o1,k2,key)
            }
        }
        __syncthreads();
    }

    #pragma unroll
    for (int r = 0; r < 4; ++r) {
        float a1 = __uint_as_float(k1[r] & 0xFFFFFFC0u);
        float a2 = __uint_as_float(k2[r] & 0xFFFFFFC0u);
        float a3 = __uint_as_float(k3[r] & 0xFFFFFFC0u);
        int l1 = (int)(k1[r] & 63u), l2 = (int)(k2[r] & 63u), l3 = (int)(k3[r] & 63u);
        int b1 = (l1 >> 2) * TC + (l1 & 3) * 16 + col16;
        int b2 = (l2 >> 2) * TC + (l2 & 3) * 16 + col16;
        int b3 = (l3 >> 2) * TC + (l3 & 3) * 16 + col16;
        #pragma unroll
        for (int m = 1; m < 16; m <<= 1) {
            float o1 = __shfl_xor(a1, m, 64), o2 = __shfl_xor(a2, m, 64), o3 = __shfl_xor(a3, m, 64);
            int p1 = __shfl_xor(b1, m, 64), p2 = __shfl_xor(b2, m, 64), p3 = __shfl_xor(b3, m, 64);
            #pragma unroll
            for (int k = 0; k < 3; ++k) {
                float ov = (k == 0) ? o1 : (k == 1) ? o2 : o3;
                int oi = (k == 0) ? p1 : (k == 1) ? p2 : p3;
                if (lexless(ov, oi, a1, b1)) {
                    a3 = a2; b3 = b2; a2 = a1; b2 = b1; a1 = ov; b1 = oi;
                } else if (lexless(ov, oi, a2, b2)) {
                    a3 = a2; b3 = b2; a2 = ov; b2 = oi;
                } else if (lexless(ov, oi, a3, b3)) {
                    a3 = ov; b3 = oi;
                }
            }
        }
        if (col16 == 0) {
            int row = rowbase + koct * 4 + r;
            idx_out[row] = (float)b1;
            if (a2 - a1 < AMBIG_S) {
                if (a3 - a1 < AMBIG_S) {               // >=2 contenders near a1
                    unsigned slot = atomicAdd(fcnt, 1u);
                    fulllist[slot] = (unsigned)row;
                    fullkey[slot] = ~0ull;
                } else {                               // exactly one contender
                    unsigned slot = atomicAdd(pcnt, 1u);
                    pairlist[slot] = make_uint2((unsigned)row,
                                                ((unsigned)b1 << 16) | (unsigned)b2);
                }
            }
        }
    }
}

// np-pairwise ||z||^2, replicated in every 16-lane group.
__device__ inline float szn_wave(const float* __restrict__ zrow, int lane) {
    int sub = lane & 15;
    int hb = sub >> 3;
    int j = sub & 7;
    const float* a = zrow + hb * 128 + j;
    float v0 = a[0];
    float c = __fmul_rn(v0, v0);
    #pragma unroll
    for (int i = 1; i < 16; ++i) {
        float w = a[8 * i];
        c = __fadd_rn(c, __fmul_rn(w, w));
    }
    float p;
    p = __shfl_xor(c, 1, 64); c = __fadd_rn(c, p);
    p = __shfl_xor(c, 2, 64); c = __fadd_rn(c, p);
    p = __shfl_xor(c, 4, 64); c = __fadd_rn(c, p);
    p = __shfl_xor(c, 8, 64); c = __fadd_rn(c, p);
    return c;
}

// pair rescore: wave-per-row, 2 exact fp64 dots, np-emulated dref, lex-min.
__global__ __launch_bounds__(256) void vq_fixpair(const float* __restrict__ z,
                                                  const float* __restrict__ cb,
                                                  const float* __restrict__ sen,
                                                  const unsigned* __restrict__ pcnt,
                                                  const uint2* __restrict__ pairlist,
                                                  float* __restrict__ idx_out) {
    int wave = blockIdx.x * 4 + (threadIdx.x >> 6);
    int lane = threadIdx.x & 63;
    int half = lane >> 5, s5 = lane & 31;
    int n = (int)*pcnt;
    for (int w = wave; w < n; w += PAIR_GRID * 4) {
        uint2 pr = pairlist[w];
        int row = (int)pr.x;
        int c1 = (int)(pr.y >> 16), c2 = (int)(pr.y & 0xffffu);
        const float* zrow = z + (size_t)row * DIM;
        float sz = szn_wave(zrow, lane);
        int c = half ? c2 : c1;
        const float* zp = zrow + s5 * 8;
        const float* ep = cb + (size_t)c * DIM + s5 * 8;
        float4 za = *(const float4*)zp, zb = *(const float4*)(zp + 4);
        float4 ea = *(const float4*)ep, eb = *(const float4*)(ep + 4);
        double acc = (double)ea.x * za.x + (double)ea.y * za.y
                   + (double)ea.z * za.z + (double)ea.w * za.w
                   + (double)eb.x * zb.x + (double)eb.y * zb.y
                   + (double)eb.z * zb.z + (double)eb.w * zb.w;
        #pragma unroll
        for (int m = 1; m < 32; m <<= 1) acc += __shfl_xor(acc, m, 64);
        double d2 = __shfl(acc, 32, 64);            // lane0 reads half-1 dot
        if (lane == 0) {
            float A1 = __fadd_rn(sz, sen[c1]);
            float dref1 = __fmaf_rn(-2.0f, (float)acc, A1);
            float A2 = __fadd_rn(sz, sen[c2]);
            float dref2 = __fmaf_rn(-2.0f, (float)d2, A2);
            int win = lexless(dref1, c1, dref2, c2) ? c1 : c2;
            idx_out[row] = (float)win;
        }
    }
}

// full np-exact rescan, chunked: work item = (full row, 64-code chunk), one
// WAVE each (block = 64 thr, LDS ~66KB, 2 blocks/CU). Chunk staged coalesced
// into LDS [64][257] (pad -> (lane+d)%32 banks, 2-way free); lane = code,
// 4-accumulator fp64 dot (NO cross-lane per-code reduce); 6-step lex-min
// butterfly; one atomicMin(u64 (dref_bits<<32)|code) per chunk = global
// lex-min across chunks = np first-index argmin.
__global__ __launch_bounds__(64) void vq_fixfull(const float* __restrict__ z,
                                                 const float* __restrict__ cb,
                                                 const float* __restrict__ sen,
                                                 const unsigned* __restrict__ fcnt,
                                                 const unsigned* __restrict__ fulllist,
                                                 u64* __restrict__ fullkey) {
    __shared__ float et[64 * 257];
    __shared__ float zs[DIM];
    const int t = threadIdx.x;
    unsigned nitems = (*fcnt) * 16u;
    for (unsigned item = blockIdx.x; item < nitems; item += FULL_GRID) {
        int slot = (int)(item >> 4);
        int row = (int)fulllist[slot];
        int c0 = (int)(item & 15u) * 64;
        // stage 64 codes x 256 dims (64KB) coalesced
        #pragma unroll 8
        for (int i = 0; i < 64; ++i) {
            int g4 = i * 64 + t;
            int code = g4 >> 6, d0 = (g4 & 63) * 4;
            float4 v = *(const float4*)(cb + (size_t)(c0 + code) * DIM + d0);
            int base = code * 257 + d0;
            et[base] = v.x; et[base + 1] = v.y; et[base + 2] = v.z; et[base + 3] = v.w;
        }
        {
            float4 v = *(const float4*)(z + (size_t)row * DIM + t * 4);
            zs[t * 4] = v.x; zs[t * 4 + 1] = v.y; zs[t * 4 + 2] = v.z; zs[t * 4 + 3] = v.w;
        }
        __syncthreads();
        float sz = szn_wave(zs, t);
        // lane t owns code c0+t: 256-dim fp64 dot, 4 independent chains
        const int rb = t * 257;
        double a0 = 0.0, a1 = 0.0, a2 = 0.0, a3 = 0.0;
        #pragma unroll 16
        for (int d = 0; d < DIM; d += 4) {
            a0 += (double)et[rb + d]     * (double)zs[d];
            a1 += (double)et[rb + d + 1] * (double)zs[d + 1];
            a2 += (double)et[rb + d + 2] * (double)zs[d + 2];
            a3 += (double)et[rb + d + 3] * (double)zs[d + 3];
        }
        double dot = (a0 + a1) + (a2 + a3);
        int c = c0 + t;
        float A = __fadd_rn(sz, sen[c]);
        float dref = __fmaf_rn(-2.0f, (float)dot, A);
        float bv = dref; int bi = c;
        #pragma unroll
        for (int m = 1; m < 64; m <<= 1) {
            float ov = __shfl_xor(bv, m, 64);
            int oi = __shfl_xor(bi, m, 64);
            if (lexless(ov, oi, bv, bi)) { bv = ov; bi = oi; }
        }
        if (t == 0) {
            u64 key = ((u64)__float_as_uint(bv) << 32) | (unsigned)bi;
            atomicMin(&fullkey[slot], key);
        }
        __syncthreads();
    }
}

// unpack per-slot winners -> idx (runs after fixfull, before gather)
__global__ __launch_bounds__(256) void vq_resolve(const unsigned* __restrict__ fcnt,
                                                  const unsigned* __restrict__ fulllist,
                                                  const u64* __restrict__ fullkey,
                                                  float* __restrict__ idx_out) {
    int n = (int)*fcnt;
    for (int i = threadIdx.x; i < n; i += 256)
        idx_out[fulllist[i]] = (float)(unsigned)(fullkey[i] & 0xFFFFFFFFu);
}

// quantized_ste + commitment loss + histogram. Per-block loss partials.
__global__ __launch_bounds__(256) void vq_gather(const float* __restrict__ z,
                                                 const float* __restrict__ cb,
                                                 const float* __restrict__ idxf,
                                                 float* __restrict__ qout,
                                                 unsigned* __restrict__ hist,
                                                 double* __restrict__ partials) {
    const int tid = threadIdx.x;
    double lacc = 0.0;
    #pragma unroll
    for (int it = 0; it < GATHER_ITERS; ++it) {
        int g = it * (GATHER_BLOCKS * 256) + blockIdx.x * 256 + tid;
        int row = g >> 6, c4 = g & 63;
        int idx = (int)idxf[row];
        if (c4 == 0) atomicAdd(&hist[idx], 1u);
        float4 zv = *(const float4*)(z + (size_t)g * 4);
        float4 qv = *(const float4*)(cb + (size_t)idx * DIM + c4 * 4);
        float dx = qv.x - zv.x, dy = qv.y - zv.y, dz = qv.z - zv.z, dw = qv.w - zv.w;
        float4 o;
        o.x = zv.x + dx; o.y = zv.y + dy; o.z = zv.z + dz; o.w = zv.w + dw;
        *(float4*)(qout + (size_t)g * 4) = o;
        lacc += (double)(dx * dx + dy * dy + dz * dz + dw * dw);
    }
    #pragma unroll
    for (int off = 32; off; off >>= 1) lacc += __shfl_down(lacc, off, 64);
    __shared__ double wsum[4];
    int lane = tid & 63, wv = tid >> 6;
    if (lane == 0) wsum[wv] = lacc;
    __syncthreads();
    if (tid == 0)
        partials[blockIdx.x] = (wsum[0] + wsum[1]) + (wsum[2] + wsum[3]);
}

// reduce 1024 loss partials (double) + hist entropy -> 3 scalars
__global__ __launch_bounds__(1024) void vq_finalize(const unsigned* __restrict__ hist,
                                                    const double* __restrict__ partials,
                                                    float* __restrict__ out) {
    __shared__ float red[1024];
    __shared__ double redd[1024];
    int t = threadIdx.x;
    float p = (float)hist[t] * (1.0f / (float)N_ROWS);
    red[t] = p * logf(p + 1e-10f);
    redd[t] = partials[t];
    __syncthreads();
    for (int s = 512; s; s >>= 1) {
        if (t < s) { red[t] += red[t + s]; redd[t] += redd[t + s]; }
        __syncthreads();
    }
    if (t == 0) {
        out[ZERO_OFF] = 0.0f;
        out[LOSS_OFF] = (float)(0.25 * redd[0] / (double)Q_N);
        out[PERP_OFF] = expf(-red[0]);
    }
}

extern "C" void kernel_launch(void* const* d_in, const int* in_sizes, int n_in,
                              void* d_out, int out_size, void* d_ws, size_t ws_size,
                              hipStream_t stream) {
    const float* z = (const float*)d_in[0];
    const float* cb = (const float*)d_in[1];
    float* out = (float*)d_out;

    float* sen = (float*)d_ws;
    unsigned* hist = (unsigned*)((char*)d_ws + 4096);
    unsigned* pcnt = (unsigned*)((char*)d_ws + 8192);
    unsigned* fcnt = (unsigned*)((char*)d_ws + 8196);
    uint2* pairlist = (uint2*)((char*)d_ws + 8448);
    unsigned* fulllist = (unsigned*)((char*)d_ws + 270592);
    u16* e16 = (u16*)((char*)d_ws + 401664);
    double* partials = (double*)((char*)d_ws + 925952);
    u64* fullkey = (u64*)((char*)d_ws + 934144);

    vq_prep_cb<<<KCODES / 4, 256, 0, stream>>>(cb, sen, e16, hist, pcnt, fcnt);
    vq_mfma<<<N_ROWS / 64, 256, 0, stream>>>(z, e16, sen, out + IDX_OFF,
                                             pcnt, pairlist, fcnt, fulllist, fullkey);
    vq_fixpair<<<PAIR_GRID, 256, 0, stream>>>(z, cb, sen, pcnt, pairlist, out + IDX_OFF);
    vq_fixfull<<<FULL_GRID, 64, 0, stream>>>(z, cb, sen, fcnt, fulllist, fullkey);
    vq_resolve<<<1, 256, 0, stream>>>(fcnt, fulllist, fullkey, out + IDX_OFF);
    vq_gather<<<GATHER_BLOCKS, 256, 0, stream>>>(z, cb, out + IDX_OFF, out, hist, partials);
    vq_finalize<<<1, 1024, 0, stream>>>(hist, partials, out);
}